// Round 1
// 73.678 us; speedup vs baseline: 1.0418x; 1.0418x over previous
//
#include <hip/hip_runtime.h>
#include <math.h>

// ---------------------------------------------------------------------------
// FullyQuantumRNN, round 12: stall-hunt on the fused one-kernel structure.
// R11 ledger: total 76.8us = ~41us workspace-poison fill (harness floor, 82%
// HBM peak) + ~30-35us kernel whose busy-cycle model is only ~4us -> the
// kernel is stall-dominated. R12 removes the three identifiable stall makers:
//  - W[3][3] / C3[] / S3[] runtime-indexed const arrays (rule #20: scratch or
//    .rodata loads, ~100/thread in C1+C2) -> branchless cndmask selects
//  - phase-2 serial loop: 2 dependent ds_read_b32 per iter (latency ~120cy >
//    ~40cy chain) -> preload all 64 C coefs to regs, full unroll, and fold the
//    per-lane (p,q) select into the cos ARGUMENT (2 v_cos/iter instead of 4)
//  - phase-1 rolled loop's 28 v_mov av<-nv copies per row -> unroll-2
//    ping-pong (named bA/bB, prefetch-1 pattern preserved)
//  - launch_bounds (256,3)->(256,2): grid is 512 = exactly 2 blocks/CU, the
//    3rd slot never fills; free the register allocator.
// Everything else (stage A/B/C structure, GMASK/FMASK storage-frame algebra,
// DPP butterfly, readout) is R2-R11-validated and kept verbatim.
// ---------------------------------------------------------------------------

// ---- compile-time permutation algebra (R1..R10-verified) ----
constexpr int cnot_ct(int idx, int c, int t) {
    return (idx & (1 << (4 - c))) ? (idx ^ (1 << (4 - t))) : idx;
}
constexpr int Pfwd_ct(int x, int r) {            // new[i] = old[Pfwd(i)]
    for (int w = 4; w >= 0; --w) x = cnot_ct(x, w, (w + r) % 5);
    return x;
}
constexpr int Pinv_ct(int x, int r) {
    for (int w = 0; w <= 4; ++w) x = cnot_ct(x, w, (w + r) % 5);
    return x;
}
static_assert(Pinv_ct(Pfwd_ct(13, 1), 1) == 13, "inv1");
static_assert(Pinv_ct(Pfwd_ct(22, 2), 2) == 22, "inv2");

// gate pair masks (storage-frame) and row-select functionals
constexpr int GMASK[10] = {16, 8, 4, 2, 1,
                           Pfwd_ct(16,1), Pfwd_ct(8,1), Pfwd_ct(4,1), Pfwd_ct(2,1), Pfwd_ct(1,1)};
constexpr int fmask_l1(int pb) {
    int f = 0;
    for (int b = 0; b < 5; ++b) if ((Pinv_ct(1 << b, 1) >> pb) & 1) f |= 1 << b;
    return f;
}
constexpr int FMASK[10] = {16, 8, 4, 2, 1,
                           fmask_l1(4), fmask_l1(3), fmask_l1(2), fmask_l1(1), fmask_l1(0)};
// expZ sign functionals on the storage index (final wires 3,4)
constexpr int cinv_ct(int x) { return Pinv_ct(Pinv_ct(x, 1), 2); }
constexpr int fmask_fin(int pb) {
    int f = 0;
    for (int b = 0; b < 5; ++b) if ((cinv_ct(1 << b) >> pb) & 1) f |= 1 << b;
    return f;
}
constexpr int SF3 = fmask_fin(1);
constexpr int SF4 = fmask_fin(0);

// each gate's pair must straddle its row-functional (one beta=0, one beta=1)
constexpr bool gates_straddle() {
    for (int g = 0; g < 10; ++g)
        if (!(__builtin_popcount(GMASK[g] & FMASK[g]) & 1)) return false;
    return true;
}
static_assert(gates_straddle(), "GMASK/FMASK straddle");

// phase-2 butterfly {1,2,7} spans 8-lane halves (R6-validated scheme)
constexpr unsigned span3_ct(int a, int b, int c) {
    unsigned m = 0;
    for (int i = 0; i < 8; ++i) {
        int v = ((i & 1) ? a : 0) ^ ((i & 2) ? b : 0) ^ ((i & 4) ? c : 0);
        m |= 1u << v;
    }
    return m;
}
static_assert(span3_ct(1, 2, 7) == 0xFFu, "butterfly {1,2,7} spans lanes 0..7");

__device__ __forceinline__ int pinv_rt(int x, int r) {
    #pragma unroll
    for (int w = 0; w < 5; ++w) {
        int cbit = 1 << (4 - w), tbit = 1 << (4 - ((w + r) % 5));
        if (x & cbit) x ^= tbit;
    }
    return x;
}

// ---- W = V^-1 rows, branchless (NO runtime-indexed array -> no scratch) ----
// W[0]={1/3,1/3,1/3}  W[1]={2/3,-1/3,-1/3}  W[2]={0,+s3,-s3}
__device__ __forceinline__ float Wsel(int r, int d) {
    float b, c;
    if (d == 0)      { b =  2.f / 3.f; c = 0.f; }
    else if (d == 1) { b = -1.f / 3.f; c =  0.57735026918962576f; }
    else             { b = -1.f / 3.f; c = -0.57735026918962576f; }
    return (r == 0) ? (1.f / 3.f) : ((r == 1) ? b : c);
}

// ---- cross-lane xor via DPP (phase-2 recurrence only; within 16-lane rows) --
template<int CTRL> __device__ __forceinline__ float dppf(float x) {
    return __int_as_float(__builtin_amdgcn_mov_dpp(__float_as_int(x), CTRL, 0xF, 0xF, true));
}
template<int PL> __device__ __forceinline__ float mvf(float x) {
    if constexpr (PL == 1)      return dppf<0xB1>(x);    // quad_perm xor1
    else if constexpr (PL == 2) return dppf<0x4E>(x);    // quad_perm xor2
    else if constexpr (PL == 7) return dppf<0x141>(x);   // row_half_mirror = xor7
    else if constexpr (PL == 8) return dppf<0x128>(x);   // row_ror:8 = xor8
    else { static_assert(PL == 1 || PL == 2 || PL == 7 || PL == 8, "mask"); return x; }
}

// ---- full-state Ry in storage frame: pair mask m, row functional F ----
template<int g>
__device__ __forceinline__ void gate_full(float (&ar)[32], float (&ai)[32],
                                          float c, float s) {
    constexpr int m = GMASK[g], F = FMASK[g];
    #pragma unroll
    for (int i = 0; i < 32; ++i) {
        if ((__builtin_popcount(i & F) & 1) == 0) {   // beta=0 member of pair
            const int j = i ^ m;                      // beta=1 (straddle assert)
            const float r0 = ar[i], i0 = ai[i], r1 = ar[j], i1 = ai[j];
            ar[i] = c * r0 - s * r1;  ai[i] = c * i0 - s * i1;
            ar[j] = s * r0 + c * r1;  ai[j] = s * i0 + c * i1;
        }
    }
}

__global__ __launch_bounds__(256, 2) void qrnn_fused(
    const float* __restrict__ x_seq, const float* __restrict__ w_rec,
    const float* __restrict__ w_out, float* __restrict__ out, int B) {

    __shared__ __align__(16) float4 xs4[16 * 33];     // staged x, padded rows
    __shared__ __align__(16) float A2s[18 * 28];      // contracted A, padded
    __shared__ float CgS[10], SgS[10];                // cos/sin(theta_g/2)
    __shared__ float P0c[32], P0s[32], E1c[32], E1s[32];
    __shared__ float RC[16];                          // readout coefs
    __shared__ __align__(16) float Cm_pool[16 * 19 * 33];   // Cm; aliases Qs/P1s
    float* const Qs  = Cm_pool;                       // [486] eval results
    float* const P1s = Cm_pool + 512;                 // [486] C1 partials

    const int tloc = threadIdx.x;
    const int grp  = tloc >> 4;
    const int k    = tloc & 15;
    const int b0   = blockIdx.x * 16;
    const int b    = b0 + grp;

    // ---- stage x (coalesced; consumed after barriers below) ----
    #pragma unroll
    for (int qq = 0; qq < 2; ++qq) {
        const int p = tloc + qq * 256;
        const int ts = p >> 4, lbs = p & 15;
        const int gidx = (ts * B + (b0 + lbs)) * 3;
        float4 v;
        v.x = x_seq[gidx]; v.y = x_seq[gidx + 1]; v.z = x_seq[gidx + 2]; v.w = 0.f;
        xs4[lbs * 33 + ts] = v;
    }

    // ---- stage A: all libm trig, distributed (depth ~2 calls) ----
    if (tloc < 10) {
        const float th = w_rec[(tloc / 5) * 15 + (tloc % 5) * 3 + 1];
        CgS[tloc] = cosf(0.5f * th);
        SgS[tloc] = sinf(0.5f * th);
    } else if (tloc >= 32 && tloc < 96) {
        const int idx = tloc - 32;
        const int i = idx & 31;
        float ang = 0.f;
        if (idx < 32) {                         // D_phi0 phase per amp
            #pragma unroll
            for (int w = 0; w < 5; ++w)
                ang += (((i >> (4 - w)) & 1) ? 0.5f : -0.5f) * w_rec[w * 3 + 0];
            P0c[i] = cosf(ang); P0s[i] = sinf(ang);
        } else {                                // E1 = D_w0 * P1-frame D_phi1
            const int j = pinv_rt(i, 1);
            #pragma unroll
            for (int w = 0; w < 5; ++w) {
                ang += (((i >> (4 - w)) & 1) ? 0.5f : -0.5f) * w_rec[w * 3 + 2];
                ang += (((j >> (4 - w)) & 1) ? 0.5f : -0.5f) * w_rec[15 + w * 3 + 0];
            }
            E1c[i] = cosf(ang); E1s[i] = sinf(ang);
        }
    } else if (tloc >= 96 && tloc < 100) {      // readout gate coefs
        const int g = tloc - 96;                // g = li*2 + w
        const int li = g >> 1, w = g & 1;
        const float phi = w_out[li * 6 + w * 3 + 0];
        const float the = w_out[li * 6 + w * 3 + 1];
        const float ome = w_out[li * 6 + w * 3 + 2];
        const float cs = cosf(0.5f * the), ss = sinf(0.5f * the);
        const float cp = cosf(0.5f * (phi + ome)), sp = sinf(0.5f * (phi + ome));
        const float cm = cosf(0.5f * (phi - ome)), sm = sinf(0.5f * (phi - ome));
        RC[g * 4 + 0] = cp * cs;
        RC[g * 4 + 1] = -sp * cs;
        RC[g * 4 + 2] = cm * ss;
        RC[g * 4 + 3] = sm * ss;
    }
    __syncthreads();

    // ---- stage B: per-thread full-state eval at exact combo angles ----
    if (tloc < 243) {
        const int d0 = tloc / 81, d1 = (tloc / 27) % 3, d2 = (tloc / 9) % 3,
                  d3 = (tloc / 3) % 3, d4 = tloc % 3;
        // eval-angle factors, branchless (same constants as old C3[]/S3[]):
        // c: {1, 0.5, 0.5}   s: {0, +0.866.., -0.866..}
        constexpr float S3v = 0.86602540378443865f;
        const float f0c = (d0 == 0) ? 1.f : 0.5f;
        const float f0s = (d0 == 0) ? 0.f : ((d0 == 1) ? S3v : -S3v);
        const float f1c = (d1 == 0) ? 1.f : 0.5f;
        const float f1s = (d1 == 0) ? 0.f : ((d1 == 1) ? S3v : -S3v);
        const float f2c = (d2 == 0) ? 1.f : 0.5f;
        const float f2s = (d2 == 0) ? 0.f : ((d2 == 1) ? S3v : -S3v);
        const float f3c = (d3 == 0) ? 1.f : 0.5f;
        const float f3s = (d3 == 0) ? 0.f : ((d3 == 1) ? S3v : -S3v);
        const float f4c = (d4 == 0) ? 1.f : 0.5f;
        const float f4s = (d4 == 0) ? 0.f : ((d4 == 1) ? S3v : -S3v);

        float ar[32], ai[32];
        #pragma unroll
        for (int i = 0; i < 32; ++i) {          // product state * D_phi0
            const float bb = ((i & 16) ? f0s : f0c) * ((i & 8) ? f1s : f1c) *
                             ((i & 4) ? f2s : f2c) * ((i & 2) ? f3s : f3c) *
                             ((i & 1) ? f4s : f4c);
            ar[i] = bb * P0c[i]; ai[i] = bb * P0s[i];
        }
        // layer 0 (masks e_w, rows by own bit)
        gate_full<0>(ar, ai, CgS[0], SgS[0]);
        gate_full<1>(ar, ai, CgS[1], SgS[1]);
        gate_full<2>(ar, ai, CgS[2], SgS[2]);
        gate_full<3>(ar, ai, CgS[3], SgS[3]);
        gate_full<4>(ar, ai, CgS[4], SgS[4]);
        // merged diagonal E1 (D_omega1 dropped: phase-blind)
        #pragma unroll
        for (int i = 0; i < 32; ++i) {
            const float nr = ar[i] * E1c[i] - ai[i] * E1s[i];
            const float ni = ar[i] * E1s[i] + ai[i] * E1c[i];
            ar[i] = nr; ai[i] = ni;
        }
        // layer 1 in storage frame (GMASK/FMASK functionals, no permute)
        gate_full<5>(ar, ai, CgS[5], SgS[5]);
        gate_full<6>(ar, ai, CgS[6], SgS[6]);
        gate_full<7>(ar, ai, CgS[7], SgS[7]);
        gate_full<8>(ar, ai, CgS[8], SgS[8]);
        gate_full<9>(ar, ai, CgS[9], SgS[9]);
        // expZ via SF3/SF4 sign functionals (R2-R8-validated)
        float q0 = 0.f, q1 = 0.f;
        #pragma unroll
        for (int i = 0; i < 32; ++i) {
            const float p = ar[i] * ar[i] + ai[i] * ai[i];
            q0 += (__builtin_popcount(i & SF3) & 1) ? -p : p;
            q1 += (__builtin_popcount(i & SF4) & 1) ? -p : p;
        }
        *reinterpret_cast<float2*>(&Qs[tloc * 2]) = make_float2(q0, q1);
    }
    __syncthreads();

    // ---- stage C1: contract d3,d4 (Wsel = branchless V^-1 rows) ----
    for (int o = tloc; o < 486; o += 256) {
        const int j = o & 1, e = o >> 1;
        const int d012 = e / 9, pq = e % 9, pp = pq / 3, qq2 = pq % 3;
        float acc = 0.f;
        #pragma unroll
        for (int d3 = 0; d3 < 3; ++d3) {
            const float wp = Wsel(pp, d3);
            #pragma unroll
            for (int d4 = 0; d4 < 3; ++d4)
                acc = fmaf(wp * Wsel(qq2, d4), Qs[(d012 * 9 + d3 * 3 + d4) * 2 + j], acc);
        }
        P1s[(d012 * 9 + pq) * 2 + j] = acc;
    }
    __syncthreads();

    // ---- stage C2: contract d0,d1,d2 -> A2s[row=j*9+pq][col=a0*9+a1*3+a2] ----
    for (int o = tloc; o < 486; o += 256) {
        const int row = o / 27, col = o % 27;
        const int j = row / 9, pq = row % 9;
        const int a0 = col / 9, a1 = (col / 3) % 3, a2 = col % 3;
        float acc = 0.f;
        #pragma unroll
        for (int dd0 = 0; dd0 < 3; ++dd0) {
            const float w0 = Wsel(a0, dd0);
            #pragma unroll
            for (int dd1 = 0; dd1 < 3; ++dd1) {
                const float w01 = w0 * Wsel(a1, dd1);
                #pragma unroll
                for (int dd2 = 0; dd2 < 3; ++dd2)
                    acc = fmaf(w01 * Wsel(a2, dd2),
                               P1s[((dd0 * 9 + dd1 * 3 + dd2) * 9 + pq) * 2 + j], acc);
            }
        }
        A2s[row * 28 + col] = acc;
    }
    if (tloc < 18) A2s[tloc * 28 + 27] = 0.f;
    __syncthreads();   // A2s ready; Qs/P1s dead -> Cm_pool reusable

    // ---- phase 1: C[t][row] = A-row . Xb(t); lane (grp,k) -> t = k, k+16 ----
    constexpr float Kf = 0.15915494309189535f;   // 1/(2*pi)
    float Xb0[28], Xb1[28];
    #pragma unroll
    for (int tt = 0; tt < 2; ++tt) {
        float* Xb = tt ? Xb1 : Xb0;
        const float4 xv = xs4[grp * 33 + k + 16 * tt];
        const float cx0 = __builtin_amdgcn_cosf(xv.x * Kf);
        const float sx0 = __builtin_amdgcn_cosf(fmaf(xv.x, Kf, -0.25f));
        const float cx1 = __builtin_amdgcn_cosf(xv.y * Kf);
        const float sx1 = __builtin_amdgcn_cosf(fmaf(xv.y, Kf, -0.25f));
        const float cx2 = __builtin_amdgcn_cosf(xv.z * Kf);
        const float sx2 = __builtin_amdgcn_cosf(fmaf(xv.z, Kf, -0.25f));
        Xb[0] = 1.f;  Xb[1] = cx2;       Xb[2] = sx2;
        Xb[3] = cx1;  Xb[4] = cx1 * cx2; Xb[5] = cx1 * sx2;
        Xb[6] = sx1;  Xb[7] = sx1 * cx2; Xb[8] = sx1 * sx2;
        #pragma unroll
        for (int i = 0; i < 9; ++i) { Xb[9 + i] = cx0 * Xb[i]; Xb[18 + i] = sx0 * Xb[i]; }
        Xb[27] = 0.f;
    }
    {
        const float4* Ap = (const float4*)A2s;      // wave-uniform LDS reads
        float* const Cmg = Cm_pool + grp * (19 * 33);
        // unroll-2 ping-pong: prefetch-1 pattern, no av<-nv register copies
        float4 bA[7], bB[7];
        #pragma unroll
        for (int i = 0; i < 7; ++i) bA[i] = Ap[i];
        #pragma unroll
        for (int i = 0; i < 7; ++i) bB[i] = Ap[7 + i];
        #pragma unroll 1
        for (int r = 0; r < 18; r += 2) {
            {
                float a00 = 0.f, a01 = 0.f, a10 = 0.f, a11 = 0.f;
                #pragma unroll
                for (int i = 0; i < 7; ++i) {
                    a00 = fmaf(bA[i].x, Xb0[4*i+0], a00); a00 = fmaf(bA[i].y, Xb0[4*i+1], a00);
                    a01 = fmaf(bA[i].z, Xb0[4*i+2], a01); a01 = fmaf(bA[i].w, Xb0[4*i+3], a01);
                    a10 = fmaf(bA[i].x, Xb1[4*i+0], a10); a10 = fmaf(bA[i].y, Xb1[4*i+1], a10);
                    a11 = fmaf(bA[i].z, Xb1[4*i+2], a11); a11 = fmaf(bA[i].w, Xb1[4*i+3], a11);
                }
                Cmg[r * 33 + k]      = a00 + a01;
                Cmg[r * 33 + k + 16] = a10 + a11;
                if (r < 16) {
                    #pragma unroll
                    for (int i = 0; i < 7; ++i) bA[i] = Ap[(r + 2) * 7 + i];
                }
            }
            {
                float a00 = 0.f, a01 = 0.f, a10 = 0.f, a11 = 0.f;
                #pragma unroll
                for (int i = 0; i < 7; ++i) {
                    a00 = fmaf(bB[i].x, Xb0[4*i+0], a00); a00 = fmaf(bB[i].y, Xb0[4*i+1], a00);
                    a01 = fmaf(bB[i].z, Xb0[4*i+2], a01); a01 = fmaf(bB[i].w, Xb0[4*i+3], a01);
                    a10 = fmaf(bB[i].x, Xb1[4*i+0], a10); a10 = fmaf(bB[i].y, Xb1[4*i+1], a10);
                    a11 = fmaf(bB[i].z, Xb1[4*i+2], a11); a11 = fmaf(bB[i].w, Xb1[4*i+3], a11);
                }
                Cmg[(r + 1) * 33 + k]      = a00 + a01;
                Cmg[(r + 1) * 33 + k + 16] = a10 + a11;
                if (r < 16) {
                    #pragma unroll
                    for (int i = 0; i < 7; ++i) bB[i] = Ap[(r + 3) * 7 + i];
                }
            }
        }
        Cmg[18 * 33 + k] = 0.f; Cmg[18 * 33 + k + 16] = 0.f;
    }
    // Cm written/read within the same 16-lane group -> no barrier (validated)

    // ---- phase 2: recurrence; lane k = coefficient slot ----
    // R12: all 64 C coefs preloaded to regs (no LDS reads on the serial
    // chain), full unroll (static indices), and per-lane-constant (p,q)
    // folded into the cos argument: u = cos(fma(h0,Kfu,bu)) -> 2 v_cos/iter.
    const int jj = k >> 3;
    const int term = (k & 7) + 1;
    const int rowA = jj * 9 + term;
    const int rowB = (k == 0) ? 0 : ((k == 8) ? 9 : 18);
    const int p = term / 3, q = term % 3;
    const float* CA_ptr = Cm_pool + grp * (19 * 33) + rowA * 33;
    const float* CB_ptr = Cm_pool + grp * (19 * 33) + rowB * 33;

    float CAr[32], CBr[32];
    #pragma unroll
    for (int t = 0; t < 32; ++t) { CAr[t] = CA_ptr[t]; CBr[t] = CB_ptr[t]; }

    const float Kfu = (p == 0) ? 0.f : Kf;       // cos(0)=1 for p==0 lanes
    const float bu  = (p == 2) ? -0.25f : 0.f;   // -0.25 rev = sin
    const float Kfv = (q == 0) ? 0.f : Kf;
    const float bv  = (q == 2) ? -0.25f : 0.f;

    float h0 = 0.f, h1 = 0.f;
    #pragma unroll
    for (int t = 0; t < 32; ++t) {
        const float u = __builtin_amdgcn_cosf(fmaf(h0, Kfu, bu));
        const float v = __builtin_amdgcn_cosf(fmaf(h1, Kfv, bv));
        float val = fmaf(CAr[t], u * v, CBr[t]);
        val += mvf<1>(val);
        val += mvf<2>(val);
        val += mvf<7>(val);
        const float other = mvf<8>(val);
        h0 = (k & 8) ? other : val;
        h1 = (k & 8) ? val : other;
    }

    // ---- readout: precomputed coefs + HW h-trig (R10-validated) ----
    constexpr float K2 = 0.5f * 0.15915494309189535f;
    const float ch0 = __builtin_amdgcn_cosf(h0 * K2);
    const float sh0 = __builtin_amdgcn_cosf(fmaf(h0, K2, -0.25f));
    const float ch1 = __builtin_amdgcn_cosf(h1 * K2);
    const float sh1 = __builtin_amdgcn_cosf(fmaf(h1, K2, -0.25f));
    float vr0 = ch0 * ch1, vr1 = ch0 * sh1, vr2 = sh0 * ch1, vr3 = sh0 * sh1;
    float vi0 = 0.f, vi1 = 0.f, vi2 = 0.f, vi3 = 0.f;

    #pragma unroll
    for (int li = 0; li < 2; ++li) {
        #pragma unroll
        for (int w = 0; w < 2; ++w) {
            const int g = li * 2 + w;
            const float are = RC[g*4+0], aim = RC[g*4+1];
            const float bre = RC[g*4+2], bim = RC[g*4+3];
            #define AP2(r0, i0, r1, i1) do {                                  \
                float n0r = are*(r0) - aim*(i0) - bre*(r1) + bim*(i1);        \
                float n0i = are*(i0) + aim*(r0) - bre*(i1) - bim*(r1);        \
                float n1r = bre*(r0) + bim*(i0) + are*(r1) + aim*(i1);        \
                float n1i = bre*(i0) - bim*(r0) + are*(i1) - aim*(r1);        \
                r0 = n0r; i0 = n0i; r1 = n1r; i1 = n1i; } while (0)
            if (w == 0) { AP2(vr0, vi0, vr2, vi2); AP2(vr1, vi1, vr3, vi3); }
            else        { AP2(vr0, vi0, vr1, vi1); AP2(vr2, vi2, vr3, vi3); }
            #undef AP2
        }
        // CNOT(0,1) then CNOT(1,0): composed perm [0,2,3,1] (R1-verified)
        float tr1 = vr2, ti1 = vi2, tr2 = vr3, ti2 = vi3, tr3 = vr1, ti3 = vi1;
        vr1 = tr1; vi1 = ti1; vr2 = tr2; vi2 = ti2; vr3 = tr3; vi3 = ti3;
    }

    const float outv = (vr0 * vr0 + vi0 * vi0 + vr1 * vr1 + vi1 * vi1) -
                       (vr2 * vr2 + vi2 * vi2 + vr3 * vr3 + vi3 * vi3);
    if (k == 0) out[b] = outv;
}

extern "C" void kernel_launch(void* const* d_in, const int* in_sizes, int n_in,
                              void* d_out, int out_size, void* d_ws, size_t ws_size,
                              hipStream_t stream) {
    const float* x_seq = (const float*)d_in[0];
    const float* w_rec = (const float*)d_in[1];
    const float* w_out = (const float*)d_in[2];
    float* out = (float*)d_out;

    const int B = out_size;             // 8192 (T fixed at 32 by the bench)
    const int grid = (B * 16) / 256;    // 512 blocks, 2/CU

    hipLaunchKernelGGL(qrnn_fused, dim3(grid), dim3(256), 0, stream,
                       x_seq, w_rec, w_out, out, B);
}

// Round 2
// 69.120 us; speedup vs baseline: 1.1105x; 1.0659x over previous
//
#include <hip/hip_runtime.h>
#include <math.h>

// ---------------------------------------------------------------------------
// FullyQuantumRNN, round 13: concentrate redundant setup + factor layer 0.
// R12 post-mortem: -3.1us came from de-LDS-ing the serial chain; the W arrays
// were not scratch. Remaining kernel ~21us is issue-bound redundant setup
// (every wave of every block runs stage B) + phase-1 issue. R13:
//  - 512-thread blocks, 32 batches/block, grid=256 (1 block/CU, LDS 97KB).
//    Stage B (threads 0..242) now runs in 1 wave/SIMD while waves 4-7 park
//    at the barrier -> setup wave gets exclusive issue; chip-wide setup
//    redundancy halves (256 blocks vs 512).
//  - stage B rewrite: state is a PRODUCT state through layer 0 (init, D_phi0,
//    and layer-0 Ry all factor per qubit). Per-qubit complex 2-vector
//    rotation (5x12 ops) + binary product tree (60 cmults ~ 240 ops) replaces
//    init-product + P0 table + 5 gate_full (~830 ops). P0c/P0s tables dropped;
//    stage A now emits per-qubit cos/sin(phi0/2). E1 diagonal, layer-1
//    storage-frame gates, expZ: R2-R12-validated, verbatim.
//  - phase 1 / phase 2 / readout: R12 structure verbatim (32-group indexing).
// ---------------------------------------------------------------------------

// ---- compile-time permutation algebra (R1..R10-verified) ----
constexpr int cnot_ct(int idx, int c, int t) {
    return (idx & (1 << (4 - c))) ? (idx ^ (1 << (4 - t))) : idx;
}
constexpr int Pfwd_ct(int x, int r) {            // new[i] = old[Pfwd(i)]
    for (int w = 4; w >= 0; --w) x = cnot_ct(x, w, (w + r) % 5);
    return x;
}
constexpr int Pinv_ct(int x, int r) {
    for (int w = 0; w <= 4; ++w) x = cnot_ct(x, w, (w + r) % 5);
    return x;
}
static_assert(Pinv_ct(Pfwd_ct(13, 1), 1) == 13, "inv1");
static_assert(Pinv_ct(Pfwd_ct(22, 2), 2) == 22, "inv2");

// gate pair masks (storage-frame) and row-select functionals
constexpr int GMASK[10] = {16, 8, 4, 2, 1,
                           Pfwd_ct(16,1), Pfwd_ct(8,1), Pfwd_ct(4,1), Pfwd_ct(2,1), Pfwd_ct(1,1)};
constexpr int fmask_l1(int pb) {
    int f = 0;
    for (int b = 0; b < 5; ++b) if ((Pinv_ct(1 << b, 1) >> pb) & 1) f |= 1 << b;
    return f;
}
constexpr int FMASK[10] = {16, 8, 4, 2, 1,
                           fmask_l1(4), fmask_l1(3), fmask_l1(2), fmask_l1(1), fmask_l1(0)};
// expZ sign functionals on the storage index (final wires 3,4)
constexpr int cinv_ct(int x) { return Pinv_ct(Pinv_ct(x, 1), 2); }
constexpr int fmask_fin(int pb) {
    int f = 0;
    for (int b = 0; b < 5; ++b) if ((cinv_ct(1 << b) >> pb) & 1) f |= 1 << b;
    return f;
}
constexpr int SF3 = fmask_fin(1);
constexpr int SF4 = fmask_fin(0);

// each gate's pair must straddle its row-functional (one beta=0, one beta=1)
constexpr bool gates_straddle() {
    for (int g = 0; g < 10; ++g)
        if (!(__builtin_popcount(GMASK[g] & FMASK[g]) & 1)) return false;
    return true;
}
static_assert(gates_straddle(), "GMASK/FMASK straddle");

// phase-2 butterfly {1,2,7} spans 8-lane halves (R6-validated scheme)
constexpr unsigned span3_ct(int a, int b, int c) {
    unsigned m = 0;
    for (int i = 0; i < 8; ++i) {
        int v = ((i & 1) ? a : 0) ^ ((i & 2) ? b : 0) ^ ((i & 4) ? c : 0);
        m |= 1u << v;
    }
    return m;
}
static_assert(span3_ct(1, 2, 7) == 0xFFu, "butterfly {1,2,7} spans lanes 0..7");

__device__ __forceinline__ int pinv_rt(int x, int r) {
    #pragma unroll
    for (int w = 0; w < 5; ++w) {
        int cbit = 1 << (4 - w), tbit = 1 << (4 - ((w + r) % 5));
        if (x & cbit) x ^= tbit;
    }
    return x;
}

// ---- W = V^-1 rows, branchless ----
// W[0]={1/3,1/3,1/3}  W[1]={2/3,-1/3,-1/3}  W[2]={0,+s3,-s3}
__device__ __forceinline__ float Wsel(int r, int d) {
    float b, c;
    if (d == 0)      { b =  2.f / 3.f; c = 0.f; }
    else if (d == 1) { b = -1.f / 3.f; c =  0.57735026918962576f; }
    else             { b = -1.f / 3.f; c = -0.57735026918962576f; }
    return (r == 0) ? (1.f / 3.f) : ((r == 1) ? b : c);
}

// ---- cross-lane xor via DPP (phase-2 recurrence only; within 16-lane rows) --
template<int CTRL> __device__ __forceinline__ float dppf(float x) {
    return __int_as_float(__builtin_amdgcn_mov_dpp(__float_as_int(x), CTRL, 0xF, 0xF, true));
}
template<int PL> __device__ __forceinline__ float mvf(float x) {
    if constexpr (PL == 1)      return dppf<0xB1>(x);    // quad_perm xor1
    else if constexpr (PL == 2) return dppf<0x4E>(x);    // quad_perm xor2
    else if constexpr (PL == 7) return dppf<0x141>(x);   // row_half_mirror = xor7
    else if constexpr (PL == 8) return dppf<0x128>(x);   // row_ror:8 = xor8
    else { static_assert(PL == 1 || PL == 2 || PL == 7 || PL == 8, "mask"); return x; }
}

// ---- full-state Ry in storage frame: pair mask m, row functional F ----
template<int g>
__device__ __forceinline__ void gate_full(float (&ar)[32], float (&ai)[32],
                                          float c, float s) {
    constexpr int m = GMASK[g], F = FMASK[g];
    #pragma unroll
    for (int i = 0; i < 32; ++i) {
        if ((__builtin_popcount(i & F) & 1) == 0) {   // beta=0 member of pair
            const int j = i ^ m;                      // beta=1 (straddle assert)
            const float r0 = ar[i], i0 = ai[i], r1 = ar[j], i1 = ai[j];
            ar[i] = c * r0 - s * r1;  ai[i] = c * i0 - s * i1;
            ar[j] = s * r0 + c * r1;  ai[j] = s * i0 + c * i1;
        }
    }
}

__global__ __launch_bounds__(512, 2) void qrnn_fused(
    const float* __restrict__ x_seq, const float* __restrict__ w_rec,
    const float* __restrict__ w_out, float* __restrict__ out, int B) {

    __shared__ __align__(16) float4 xs4[32 * 33];     // staged x, padded rows
    __shared__ __align__(16) float A2s[18 * 28];      // contracted A, padded
    __shared__ float CgS[10], SgS[10];                // cos/sin(theta_g/2)
    __shared__ float F0c[5], F0s[5];                  // cos/sin(phi0_w/2)
    __shared__ float E1c[32], E1s[32];
    __shared__ float RC[16];                          // readout coefs
    __shared__ __align__(16) float Cm_pool[32 * 19 * 33];   // Cm; aliases Qs/P1s
    float* const Qs  = Cm_pool;                       // [486] eval results
    float* const P1s = Cm_pool + 512;                 // [486] C1 partials

    const int tloc = threadIdx.x;
    const int grp  = tloc >> 4;                       // 0..31: batch in block
    const int k    = tloc & 15;
    const int b0   = blockIdx.x * 32;
    const int b    = b0 + grp;

    // ---- stage x (coalesced; consumed after barriers below) ----
    #pragma unroll
    for (int qq = 0; qq < 2; ++qq) {
        const int p = tloc + qq * 512;
        const int ts = p >> 5, lbs = p & 31;
        const int gidx = (ts * B + (b0 + lbs)) * 3;
        float4 v;
        v.x = x_seq[gidx]; v.y = x_seq[gidx + 1]; v.z = x_seq[gidx + 2]; v.w = 0.f;
        xs4[lbs * 33 + ts] = v;
    }

    // ---- stage A: all libm trig, distributed (depth ~2 calls) ----
    if (tloc < 10) {
        const float th = w_rec[(tloc / 5) * 15 + (tloc % 5) * 3 + 1];
        CgS[tloc] = cosf(0.5f * th);
        SgS[tloc] = sinf(0.5f * th);
    } else if (tloc >= 16 && tloc < 21) {             // per-qubit phi0/2
        const int w = tloc - 16;
        const float ph = 0.5f * w_rec[w * 3 + 0];
        F0c[w] = cosf(ph); F0s[w] = sinf(ph);
    } else if (tloc >= 64 && tloc < 96) {             // E1 = D_w0 * P1-frame D_phi1
        const int i = tloc - 64;
        const int j = pinv_rt(i, 1);
        float ang = 0.f;
        #pragma unroll
        for (int w = 0; w < 5; ++w) {
            ang += (((i >> (4 - w)) & 1) ? 0.5f : -0.5f) * w_rec[w * 3 + 2];
            ang += (((j >> (4 - w)) & 1) ? 0.5f : -0.5f) * w_rec[15 + w * 3 + 0];
        }
        E1c[i] = cosf(ang); E1s[i] = sinf(ang);
    } else if (tloc >= 96 && tloc < 100) {            // readout gate coefs
        const int g = tloc - 96;                      // g = li*2 + w
        const int li = g >> 1, w = g & 1;
        const float phi = w_out[li * 6 + w * 3 + 0];
        const float the = w_out[li * 6 + w * 3 + 1];
        const float ome = w_out[li * 6 + w * 3 + 2];
        const float cs = cosf(0.5f * the), ss = sinf(0.5f * the);
        const float cp = cosf(0.5f * (phi + ome)), sp = sinf(0.5f * (phi + ome));
        const float cm = cosf(0.5f * (phi - ome)), sm = sinf(0.5f * (phi - ome));
        RC[g * 4 + 0] = cp * cs;
        RC[g * 4 + 1] = -sp * cs;
        RC[g * 4 + 2] = cm * ss;
        RC[g * 4 + 3] = sm * ss;
    }
    __syncthreads();

    // ---- stage B: per-thread full-state eval at exact combo angles ----
    // Product structure through layer 0: per-qubit 2-vector
    //   v0 = fc*e^{-i phi/2}, v1 = fs*e^{+i phi/2};  Ry: A=c*v0-s*v1, B=s*v0+c*v1
    // then binary product tree -> 32 amps (i's bit (16>>w) selects B_w vs A_w).
    if (tloc < 243) {
        const int dsel[5] = {tloc / 81, (tloc / 27) % 3, (tloc / 9) % 3,
                             (tloc / 3) % 3, tloc % 3};
        constexpr float S3v = 0.86602540378443865f;
        float Arw[5], Aiw[5], Brw[5], Biw[5];
        #pragma unroll
        for (int w = 0; w < 5; ++w) {
            const int d = dsel[w];
            const float fc = (d == 0) ? 1.f : 0.5f;
            const float fs = (d == 0) ? 0.f : ((d == 1) ? S3v : -S3v);
            const float c = CgS[w], s = SgS[w];
            const float t1 = fmaf(c, fc, -s * fs);   // c*fc - s*fs
            const float t2 = fmaf(c, fc,  s * fs);   // c*fc + s*fs
            const float t3 = fmaf(s, fc,  c * fs);   // s*fc + c*fs
            const float t4 = fmaf(c, fs, -s * fc);   // c*fs - s*fc
            Arw[w] =  F0c[w] * t1;  Aiw[w] = -F0s[w] * t2;
            Brw[w] =  F0c[w] * t3;  Biw[w] =  F0s[w] * t4;
        }
        float ar[32], ai[32];
        ar[0] = Arw[0]; ai[0] = Aiw[0]; ar[1] = Brw[0]; ai[1] = Biw[0];
        #pragma unroll
        for (int w = 1; w < 5; ++w) {
            const int n = 1 << w;
            #pragma unroll
            for (int m = n - 1; m >= 0; --m) {        // descending: in-place safe
                const float orr = ar[m], oii = ai[m];
                ar[2*m]   = fmaf(orr, Arw[w], -oii * Aiw[w]);
                ai[2*m]   = fmaf(orr, Aiw[w],  oii * Arw[w]);
                ar[2*m+1] = fmaf(orr, Brw[w], -oii * Biw[w]);
                ai[2*m+1] = fmaf(orr, Biw[w],  oii * Brw[w]);
            }
        }
        // merged diagonal E1 (D_omega1 dropped: phase-blind)
        #pragma unroll
        for (int i = 0; i < 32; ++i) {
            const float nr = ar[i] * E1c[i] - ai[i] * E1s[i];
            const float ni = ar[i] * E1s[i] + ai[i] * E1c[i];
            ar[i] = nr; ai[i] = ni;
        }
        // layer 1 in storage frame (GMASK/FMASK functionals, no permute)
        gate_full<5>(ar, ai, CgS[5], SgS[5]);
        gate_full<6>(ar, ai, CgS[6], SgS[6]);
        gate_full<7>(ar, ai, CgS[7], SgS[7]);
        gate_full<8>(ar, ai, CgS[8], SgS[8]);
        gate_full<9>(ar, ai, CgS[9], SgS[9]);
        // expZ via SF3/SF4 sign functionals (R2-R8-validated)
        float q0 = 0.f, q1 = 0.f;
        #pragma unroll
        for (int i = 0; i < 32; ++i) {
            const float p = ar[i] * ar[i] + ai[i] * ai[i];
            q0 += (__builtin_popcount(i & SF3) & 1) ? -p : p;
            q1 += (__builtin_popcount(i & SF4) & 1) ? -p : p;
        }
        *reinterpret_cast<float2*>(&Qs[tloc * 2]) = make_float2(q0, q1);
    }
    __syncthreads();

    // ---- stage C1: contract d3,d4 (Wsel = branchless V^-1 rows) ----
    for (int o = tloc; o < 486; o += 512) {
        const int j = o & 1, e = o >> 1;
        const int d012 = e / 9, pq = e % 9, pp = pq / 3, qq2 = pq % 3;
        float acc = 0.f;
        #pragma unroll
        for (int d3 = 0; d3 < 3; ++d3) {
            const float wp = Wsel(pp, d3);
            #pragma unroll
            for (int d4 = 0; d4 < 3; ++d4)
                acc = fmaf(wp * Wsel(qq2, d4), Qs[(d012 * 9 + d3 * 3 + d4) * 2 + j], acc);
        }
        P1s[(d012 * 9 + pq) * 2 + j] = acc;
    }
    __syncthreads();

    // ---- stage C2: contract d0,d1,d2 -> A2s[row=j*9+pq][col=a0*9+a1*3+a2] ----
    for (int o = tloc; o < 486; o += 512) {
        const int row = o / 27, col = o % 27;
        const int j = row / 9, pq = row % 9;
        const int a0 = col / 9, a1 = (col / 3) % 3, a2 = col % 3;
        float acc = 0.f;
        #pragma unroll
        for (int dd0 = 0; dd0 < 3; ++dd0) {
            const float w0 = Wsel(a0, dd0);
            #pragma unroll
            for (int dd1 = 0; dd1 < 3; ++dd1) {
                const float w01 = w0 * Wsel(a1, dd1);
                #pragma unroll
                for (int dd2 = 0; dd2 < 3; ++dd2)
                    acc = fmaf(w01 * Wsel(a2, dd2),
                               P1s[((dd0 * 9 + dd1 * 3 + dd2) * 9 + pq) * 2 + j], acc);
            }
        }
        A2s[row * 28 + col] = acc;
    }
    if (tloc < 18) A2s[tloc * 28 + 27] = 0.f;
    __syncthreads();   // A2s ready; Qs/P1s dead -> Cm_pool reusable

    // ---- phase 1: C[t][row] = A-row . Xb(t); lane (grp,k) -> t = k, k+16 ----
    constexpr float Kf = 0.15915494309189535f;   // 1/(2*pi)
    float Xb0[28], Xb1[28];
    #pragma unroll
    for (int tt = 0; tt < 2; ++tt) {
        float* Xb = tt ? Xb1 : Xb0;
        const float4 xv = xs4[grp * 33 + k + 16 * tt];
        const float cx0 = __builtin_amdgcn_cosf(xv.x * Kf);
        const float sx0 = __builtin_amdgcn_cosf(fmaf(xv.x, Kf, -0.25f));
        const float cx1 = __builtin_amdgcn_cosf(xv.y * Kf);
        const float sx1 = __builtin_amdgcn_cosf(fmaf(xv.y, Kf, -0.25f));
        const float cx2 = __builtin_amdgcn_cosf(xv.z * Kf);
        const float sx2 = __builtin_amdgcn_cosf(fmaf(xv.z, Kf, -0.25f));
        Xb[0] = 1.f;  Xb[1] = cx2;       Xb[2] = sx2;
        Xb[3] = cx1;  Xb[4] = cx1 * cx2; Xb[5] = cx1 * sx2;
        Xb[6] = sx1;  Xb[7] = sx1 * cx2; Xb[8] = sx1 * sx2;
        #pragma unroll
        for (int i = 0; i < 9; ++i) { Xb[9 + i] = cx0 * Xb[i]; Xb[18 + i] = sx0 * Xb[i]; }
        Xb[27] = 0.f;
    }
    {
        const float4* Ap = (const float4*)A2s;      // wave-uniform LDS reads
        float* const Cmg = Cm_pool + grp * (19 * 33);
        // unroll-2 ping-pong: prefetch-1 pattern, no register copies
        float4 bA[7], bB[7];
        #pragma unroll
        for (int i = 0; i < 7; ++i) bA[i] = Ap[i];
        #pragma unroll
        for (int i = 0; i < 7; ++i) bB[i] = Ap[7 + i];
        #pragma unroll 1
        for (int r = 0; r < 18; r += 2) {
            {
                float a00 = 0.f, a01 = 0.f, a10 = 0.f, a11 = 0.f;
                #pragma unroll
                for (int i = 0; i < 7; ++i) {
                    a00 = fmaf(bA[i].x, Xb0[4*i+0], a00); a00 = fmaf(bA[i].y, Xb0[4*i+1], a00);
                    a01 = fmaf(bA[i].z, Xb0[4*i+2], a01); a01 = fmaf(bA[i].w, Xb0[4*i+3], a01);
                    a10 = fmaf(bA[i].x, Xb1[4*i+0], a10); a10 = fmaf(bA[i].y, Xb1[4*i+1], a10);
                    a11 = fmaf(bA[i].z, Xb1[4*i+2], a11); a11 = fmaf(bA[i].w, Xb1[4*i+3], a11);
                }
                Cmg[r * 33 + k]      = a00 + a01;
                Cmg[r * 33 + k + 16] = a10 + a11;
                if (r < 16) {
                    #pragma unroll
                    for (int i = 0; i < 7; ++i) bA[i] = Ap[(r + 2) * 7 + i];
                }
            }
            {
                float a00 = 0.f, a01 = 0.f, a10 = 0.f, a11 = 0.f;
                #pragma unroll
                for (int i = 0; i < 7; ++i) {
                    a00 = fmaf(bB[i].x, Xb0[4*i+0], a00); a00 = fmaf(bB[i].y, Xb0[4*i+1], a00);
                    a01 = fmaf(bB[i].z, Xb0[4*i+2], a01); a01 = fmaf(bB[i].w, Xb0[4*i+3], a01);
                    a10 = fmaf(bB[i].x, Xb1[4*i+0], a10); a10 = fmaf(bB[i].y, Xb1[4*i+1], a10);
                    a11 = fmaf(bB[i].z, Xb1[4*i+2], a11); a11 = fmaf(bB[i].w, Xb1[4*i+3], a11);
                }
                Cmg[(r + 1) * 33 + k]      = a00 + a01;
                Cmg[(r + 1) * 33 + k + 16] = a10 + a11;
                if (r < 16) {
                    #pragma unroll
                    for (int i = 0; i < 7; ++i) bB[i] = Ap[(r + 3) * 7 + i];
                }
            }
        }
        Cmg[18 * 33 + k] = 0.f; Cmg[18 * 33 + k + 16] = 0.f;
    }
    // Cm written/read within the same 16-lane group -> no barrier (validated)

    // ---- phase 2: recurrence; lane k = coefficient slot (R12-validated) ----
    const int jj = k >> 3;
    const int term = (k & 7) + 1;
    const int rowA = jj * 9 + term;
    const int rowB = (k == 0) ? 0 : ((k == 8) ? 9 : 18);
    const int p = term / 3, q = term % 3;
    const float* CA_ptr = Cm_pool + grp * (19 * 33) + rowA * 33;
    const float* CB_ptr = Cm_pool + grp * (19 * 33) + rowB * 33;

    float CAr[32], CBr[32];
    #pragma unroll
    for (int t = 0; t < 32; ++t) { CAr[t] = CA_ptr[t]; CBr[t] = CB_ptr[t]; }

    const float Kfu = (p == 0) ? 0.f : Kf;       // cos(0)=1 for p==0 lanes
    const float bu  = (p == 2) ? -0.25f : 0.f;   // -0.25 rev = sin
    const float Kfv = (q == 0) ? 0.f : Kf;
    const float bv  = (q == 2) ? -0.25f : 0.f;

    float h0 = 0.f, h1 = 0.f;
    #pragma unroll
    for (int t = 0; t < 32; ++t) {
        const float u = __builtin_amdgcn_cosf(fmaf(h0, Kfu, bu));
        const float v = __builtin_amdgcn_cosf(fmaf(h1, Kfv, bv));
        float val = fmaf(CAr[t], u * v, CBr[t]);
        val += mvf<1>(val);
        val += mvf<2>(val);
        val += mvf<7>(val);
        const float other = mvf<8>(val);
        h0 = (k & 8) ? other : val;
        h1 = (k & 8) ? val : other;
    }

    // ---- readout: precomputed coefs + HW h-trig (R10-validated) ----
    constexpr float K2 = 0.5f * 0.15915494309189535f;
    const float ch0 = __builtin_amdgcn_cosf(h0 * K2);
    const float sh0 = __builtin_amdgcn_cosf(fmaf(h0, K2, -0.25f));
    const float ch1 = __builtin_amdgcn_cosf(h1 * K2);
    const float sh1 = __builtin_amdgcn_cosf(fmaf(h1, K2, -0.25f));
    float vr0 = ch0 * ch1, vr1 = ch0 * sh1, vr2 = sh0 * ch1, vr3 = sh0 * sh1;
    float vi0 = 0.f, vi1 = 0.f, vi2 = 0.f, vi3 = 0.f;

    #pragma unroll
    for (int li = 0; li < 2; ++li) {
        #pragma unroll
        for (int w = 0; w < 2; ++w) {
            const int g = li * 2 + w;
            const float are = RC[g*4+0], aim = RC[g*4+1];
            const float bre = RC[g*4+2], bim = RC[g*4+3];
            #define AP2(r0, i0, r1, i1) do {                                  \
                float n0r = are*(r0) - aim*(i0) - bre*(r1) + bim*(i1);        \
                float n0i = are*(i0) + aim*(r0) - bre*(i1) - bim*(r1);        \
                float n1r = bre*(r0) + bim*(i0) + are*(r1) + aim*(i1);        \
                float n1i = bre*(i0) - bim*(r0) + are*(i1) - aim*(r1);        \
                r0 = n0r; i0 = n0i; r1 = n1r; i1 = n1i; } while (0)
            if (w == 0) { AP2(vr0, vi0, vr2, vi2); AP2(vr1, vi1, vr3, vi3); }
            else        { AP2(vr0, vi0, vr1, vi1); AP2(vr2, vi2, vr3, vi3); }
            #undef AP2
        }
        // CNOT(0,1) then CNOT(1,0): composed perm [0,2,3,1] (R1-verified)
        float tr1 = vr2, ti1 = vi2, tr2 = vr3, ti2 = vi3, tr3 = vr1, ti3 = vi1;
        vr1 = tr1; vi1 = ti1; vr2 = tr2; vi2 = ti2; vr3 = tr3; vi3 = ti3;
    }

    const float outv = (vr0 * vr0 + vi0 * vi0 + vr1 * vr1 + vi1 * vi1) -
                       (vr2 * vr2 + vi2 * vi2 + vr3 * vr3 + vi3 * vi3);
    if (k == 0) out[b] = outv;
}

extern "C" void kernel_launch(void* const* d_in, const int* in_sizes, int n_in,
                              void* d_out, int out_size, void* d_ws, size_t ws_size,
                              hipStream_t stream) {
    const float* x_seq = (const float*)d_in[0];
    const float* w_rec = (const float*)d_in[1];
    const float* w_out = (const float*)d_in[2];
    float* out = (float*)d_out;

    const int B = out_size;             // 8192 (T fixed at 32 by the bench)
    const int grid = B / 32;            // 256 blocks, 1/CU (LDS ~97KB)

    hipLaunchKernelGGL(qrnn_fused, dim3(grid), dim3(512), 0, stream,
                       x_seq, w_rec, w_out, out, B);
}